// Round 1
// baseline (1256.367 us; speedup 1.0000x reference)
//
#include <hip/hip_runtime.h>
#include <math.h>

typedef unsigned int u32;
typedef unsigned long long u64;

#define N_ELEM 131072
#define NB 512                 // sort blocks per array (256 elems each)
#define BS 256
#define NP1 (N_ELEM + 1)       // 131073 prefix-sum points
#define CHUNK 512
#define NCH ((NP1 + CHUNK - 1) / CHUNK)   // 257

// ---- float <-> sortable key (ascending key order == descending float order) ----
__device__ __forceinline__ u32 f2key(float x) {
  u32 u = __float_as_uint(x);
  u32 t = (u & 0x80000000u) ? ~u : (u | 0x80000000u);  // ascending-sortable
  return ~t;                                            // flip -> descending
}
__device__ __forceinline__ float key2f(u32 k) {
  u32 t = ~k;
  u32 u = (t & 0x80000000u) ? (t ^ 0x80000000u) : ~t;
  return __uint_as_float(u);
}

// ---------------- init: build keys + payload indices ----------------
__global__ void k_init(const float* in0, const float* in1, u32* keyA, u32* idxA) {
  int arr = blockIdx.y;
  int i = blockIdx.x * BS + threadIdx.x;
  const float* p = arr ? in1 : in0;
  keyA[arr * N_ELEM + i] = f2key(p[i]);
  idxA[arr * N_ELEM + i] = (u32)i;
}

// ---------------- radix pass: histogram ----------------
__global__ void k_hist(const u32* key, u32* gHist, int shift) {
  int arr = blockIdx.y, b = blockIdx.x, t = threadIdx.x;
  __shared__ u32 h[256];
  h[t] = 0;
  __syncthreads();
  u32 k = key[arr * N_ELEM + b * BS + t];
  atomicAdd(&h[(k >> shift) & 255u], 1u);
  __syncthreads();
  // digit-major layout: entry = d*NB + b
  gHist[arr * (256 * NB) + t * NB + b] = h[t];
}

// ---------------- radix pass: exclusive scan of 256*NB = 131072 entries ----------------
__global__ __launch_bounds__(1024) void k_scan(const u32* gHist, u32* gOfs) {
  int arr = blockIdx.x, t = threadIdx.x;  // 1024 threads, 128 entries each
  const u32* h = gHist + arr * (256 * NB);
  u32* o = gOfs + arr * (256 * NB);
  u32 s = 0;
  for (int i = 0; i < 128; i++) s += h[t * 128 + i];
  __shared__ u32 sc[1024];
  sc[t] = s;
  __syncthreads();
  for (int off = 1; off < 1024; off <<= 1) {
    u32 v = (t >= off) ? sc[t - off] : 0u;
    __syncthreads();
    sc[t] += v;
    __syncthreads();
  }
  u32 run = (t == 0) ? 0u : sc[t - 1];
  for (int i = 0; i < 128; i++) {
    u32 x = h[t * 128 + i];
    o[t * 128 + i] = run;
    run += x;
  }
}

// ---------------- radix pass: stable scatter ----------------
__global__ void k_scatter(const u32* keyIn, const u32* idxIn, u32* keyOut, u32* idxOut,
                          const u32* gOfs, int shift) {
  int arr = blockIdx.y, b = blockIdx.x, t = threadIdx.x;
  int lane = t & 63, w = t >> 6;
  u32 k = keyIn[arr * N_ELEM + b * BS + t];
  u32 id = idxIn[arr * N_ELEM + b * BS + t];
  u32 d = (k >> shift) & 255u;
  // lanes with same digit (ballot multi-split)
  u64 same = ~0ull;
#pragma unroll
  for (int bit = 0; bit < 8; bit++) {
    u64 bal = __ballot((d >> bit) & 1u);
    same &= ((d >> bit) & 1u) ? bal : ~bal;
  }
  u64 below = (1ull << lane) - 1ull;
  int wrank = __popcll(same & below);
  __shared__ u32 wh[4][256];
  wh[0][t] = 0; wh[1][t] = 0; wh[2][t] = 0; wh[3][t] = 0;
  __syncthreads();
  if (wrank == 0) wh[w][d] = (u32)__popcll(same);
  __syncthreads();
  u32 off = 0;
  for (int w2 = 0; w2 < w; w2++) off += wh[w2][d];
  u32 pos = gOfs[arr * (256 * NB) + d * NB + b] + off + (u32)wrank;
  keyOut[arr * N_ELEM + pos] = k;
  idxOut[arr * N_ELEM + pos] = id;
}

// ---------------- prefix sum of y_i = s_i - (n-i), f64, 3 kernels ----------------
__global__ void k_prefix1(const u32* key, double* C, double* bsum) {
  int arr = blockIdx.y, b = blockIdx.x, t = threadIdx.x;
  int i = b * BS + t;
  float x = key2f(key[arr * N_ELEM + i]);
  double y = (double)x / 0.1 - (double)(N_ELEM - i);
  __shared__ double sc[BS];
  sc[t] = y;
  __syncthreads();
  for (int off = 1; off < BS; off <<= 1) {
    double v = (t >= off) ? sc[t - off] : 0.0;
    __syncthreads();
    sc[t] += v;
    __syncthreads();
  }
  C[arr * NP1 + i + 1] = sc[t];
  if (t == BS - 1) bsum[arr * NB + b] = sc[t];
  if (b == 0 && t == 0) C[arr * NP1] = 0.0;
}

__global__ void k_prefix2(double* bsum) {
  int arr = blockIdx.x, t = threadIdx.x;  // NB threads
  __shared__ double sc[NB];
  sc[t] = bsum[arr * NB + t];
  __syncthreads();
  for (int off = 1; off < NB; off <<= 1) {
    double v = (t >= off) ? sc[t - off] : 0.0;
    __syncthreads();
    sc[t] += v;
    __syncthreads();
  }
  double e = (t == 0) ? 0.0 : sc[t - 1];
  bsum[arr * NB + t] = e;
}

__global__ void k_prefix3(double* C, const double* bsum) {
  int arr = blockIdx.y, b = blockIdx.x, t = threadIdx.x;
  int i = b * BS + t;
  C[arr * NP1 + i + 1] += bsum[arr * NB + b];
}

// ---------------- upper hull (least concave majorant) ----------------
// level 1: per-chunk monotone chain, one thread per chunk
__global__ void k_hull1(const double* C, int* hullX, int* hullCnt) {
  int arr = blockIdx.y;
  int c = blockIdx.x * 64 + threadIdx.x;
  if (c >= NCH) return;
  const double* Ca = C + arr * NP1;
  int* st = hullX + ((size_t)arr * NCH + c) * CHUNK;
  int base = c * CHUNK;
  int end = (base + CHUNK < NP1) ? base + CHUNK : NP1;
  int top = 0;
  double cA = 0.0, cB = 0.0;  // C values of st[top-2], st[top-1]
  for (int i = base; i < end; i++) {
    double Ci = Ca[i];
    while (top >= 2) {
      int a = st[top - 2];
      double cr = (double)(st[top - 1] - a) * (Ci - cA) - (cB - cA) * (double)(i - a);
      if (cr >= 0.0) {  // st[top-1] on/below chord a->i : pop
        top--;
        cB = cA;
        cA = (top >= 2) ? Ca[st[top - 2]] : 0.0;
      } else break;
    }
    st[top] = i;
    cA = cB;
    cB = Ci;
    top++;
  }
  hullCnt[arr * NCH + c] = top;
}

// level 2: sequential merge over surviving chunk-hull vertices (1 thread per array)
__global__ void k_hull2(const double* C, const int* hullX, const int* hullCnt,
                        int* fhX, int* fhCnt) {
  int arr = blockIdx.x;
  if (threadIdx.x != 0) return;
  const double* Ca = C + arr * NP1;
  int* out = fhX + arr * NP1;
  int top = 0;
  double cA = 0.0, cB = 0.0;
  for (int c = 0; c < NCH; c++) {
    const int* lst = hullX + ((size_t)arr * NCH + c) * CHUNK;
    int cnt = hullCnt[arr * NCH + c];
    for (int k = 0; k < cnt; k++) {
      int i = lst[k];
      double Ci = Ca[i];
      while (top >= 2) {
        int a = out[top - 2];
        double cr = (double)(out[top - 1] - a) * (Ci - cA) - (cB - cA) * (double)(i - a);
        if (cr >= 0.0) {
          top--;
          cB = cA;
          cA = (top >= 2) ? Ca[out[top - 2]] : 0.0;
        } else break;
      }
      out[top] = i;
      cA = cB;
      cB = Ci;
      top++;
    }
  }
  fhCnt[arr] = top;
}

// ---------------- expand hull slopes -> primal ranks, scatter to original order ----------------
__global__ void k_expand(const u32* key, const u32* idx, const double* C,
                         const int* fhX, const int* fhCnt, double* r) {
  int arr = blockIdx.y, b = blockIdx.x, t = threadIdx.x;
  int i = b * BS + t;
  const int* fx = fhX + arr * NP1;
  int H = fhCnt[arr];
  int lo = 0, hi = H - 1;  // find k: fx[k] <= i < fx[k+1]
  while (hi - lo > 1) {
    int mid = (lo + hi) >> 1;
    if (fx[mid] <= i) lo = mid; else hi = mid;
  }
  const double* Ca = C + arr * NP1;
  int a = fx[lo], bb = fx[lo + 1];
  double v = (Ca[bb] - Ca[a]) / (double)(bb - a);
  double s = (double)key2f(key[arr * N_ELEM + i]) / 0.1;
  r[arr * N_ELEM + idx[arr * N_ELEM + i]] = s - v;
}

// ---------------- reductions (f64, fixed tree, deterministic) ----------------
__global__ void k_sum(const double* r, double* part) {
  int arr = blockIdx.y, b = blockIdx.x, t = threadIdx.x;
  __shared__ double sc[BS];
  sc[t] = r[arr * N_ELEM + b * BS + t];
  __syncthreads();
  for (int off = BS / 2; off > 0; off >>= 1) {
    if (t < off) sc[t] += sc[t + off];
    __syncthreads();
  }
  if (t == 0) part[arr * NB + b] = sc[0];
}

__global__ void k_mean(const double* part, double* means) {
  int arr = blockIdx.x, t = threadIdx.x;
  __shared__ double sc[BS];
  sc[t] = part[arr * NB + t] + part[arr * NB + t + BS];
  __syncthreads();
  for (int off = BS / 2; off > 0; off >>= 1) {
    if (t < off) sc[t] += sc[t + off];
    __syncthreads();
  }
  if (t == 0) means[arr] = sc[0] / (double)N_ELEM;
}

__global__ void k_mom(const double* r, const double* means, double* part2) {
  int b = blockIdx.x, t = threadIdx.x;
  int i = b * BS + t;
  double m0 = means[0], m1 = means[1];
  double a = r[i] - m0;
  double c = r[N_ELEM + i] - m1;
  __shared__ double s0[BS], s1[BS], s2[BS];
  s0[t] = a * c;
  s1[t] = a * a;
  s2[t] = c * c;
  __syncthreads();
  for (int off = BS / 2; off > 0; off >>= 1) {
    if (t < off) { s0[t] += s0[t + off]; s1[t] += s1[t + off]; s2[t] += s2[t + off]; }
    __syncthreads();
  }
  if (t == 0) {
    part2[b] = s0[0];
    part2[NB + b] = s1[0];
    part2[2 * NB + b] = s2[0];
  }
}

__global__ void k_final(const double* part2, float* out) {
  int t = threadIdx.x;
  __shared__ double s0[BS], s1[BS], s2[BS];
  s0[t] = part2[t] + part2[t + BS];
  s1[t] = part2[NB + t] + part2[NB + t + BS];
  s2[t] = part2[2 * NB + t] + part2[2 * NB + t + BS];
  __syncthreads();
  for (int off = BS / 2; off > 0; off >>= 1) {
    if (t < off) { s0[t] += s0[t + off]; s1[t] += s1[t + off]; s2[t] += s2[t + off]; }
    __syncthreads();
  }
  if (t == 0) out[0] = (float)(s0[0] / (sqrt(s1[0]) * sqrt(s2[0])));
}

// ---------------- host ----------------
extern "C" void kernel_launch(void* const* d_in, const int* in_sizes, int n_in,
                              void* d_out, int out_size, void* d_ws, size_t ws_size,
                              hipStream_t stream) {
  const float* in0 = (const float*)d_in[0];
  const float* in1 = (const float*)d_in[1];
  float* out = (float*)d_out;

  size_t off = 0;
  char* base = (char*)d_ws;
  auto alloc = [&](size_t bytes) -> char* {
    char* p = base + off;
    off += (bytes + 63) & ~(size_t)63;
    return p;
  };
  u32* keyA    = (u32*)alloc(sizeof(u32) * 2 * N_ELEM);
  u32* keyB    = (u32*)alloc(sizeof(u32) * 2 * N_ELEM);
  u32* idxA    = (u32*)alloc(sizeof(u32) * 2 * N_ELEM);
  u32* idxB    = (u32*)alloc(sizeof(u32) * 2 * N_ELEM);
  u32* gHist   = (u32*)alloc(sizeof(u32) * 2 * 256 * NB);
  u32* gOfs    = (u32*)alloc(sizeof(u32) * 2 * 256 * NB);
  double* C    = (double*)alloc(sizeof(double) * 2 * NP1);
  double* bsum = (double*)alloc(sizeof(double) * 2 * NB);
  int* hullX   = (int*)alloc(sizeof(int) * 2 * NCH * CHUNK);
  int* hullCnt = (int*)alloc(sizeof(int) * 2 * NCH);
  int* fhX     = (int*)alloc(sizeof(int) * 2 * NP1);
  int* fhCnt   = (int*)alloc(sizeof(int) * 2);
  double* r    = (double*)alloc(sizeof(double) * 2 * N_ELEM);
  double* part1 = (double*)alloc(sizeof(double) * 2 * NB);
  double* means = (double*)alloc(sizeof(double) * 2);
  double* part2 = (double*)alloc(sizeof(double) * 3 * NB);
  (void)ws_size; (void)in_sizes; (void)n_in; (void)out_size;

  dim3 g2(NB, 2), blk(BS);

  k_init<<<g2, blk, 0, stream>>>(in0, in1, keyA, idxA);

  u32 *kin = keyA, *iin = idxA, *kout = keyB, *iout = idxB;
  for (int p = 0; p < 4; p++) {
    k_hist<<<g2, blk, 0, stream>>>(kin, gHist, p * 8);
    k_scan<<<dim3(2), dim3(1024), 0, stream>>>(gHist, gOfs);
    k_scatter<<<g2, blk, 0, stream>>>(kin, iin, kout, iout, gOfs, p * 8);
    u32* tk = kin; kin = kout; kout = tk;
    u32* ti = iin; iin = iout; iout = ti;
  }
  // 4 passes -> sorted data back in keyA/idxA (kin/iin)

  k_prefix1<<<g2, blk, 0, stream>>>(kin, C, bsum);
  k_prefix2<<<dim3(2), dim3(NB), 0, stream>>>(bsum);
  k_prefix3<<<g2, blk, 0, stream>>>(C, bsum);

  k_hull1<<<dim3((NCH + 63) / 64, 2), dim3(64), 0, stream>>>(C, hullX, hullCnt);
  k_hull2<<<dim3(2), dim3(64), 0, stream>>>(C, hullX, hullCnt, fhX, fhCnt);

  k_expand<<<g2, blk, 0, stream>>>(kin, iin, C, fhX, fhCnt, r);

  k_sum<<<g2, blk, 0, stream>>>(r, part1);
  k_mean<<<dim3(2), blk, 0, stream>>>(part1, means);
  k_mom<<<dim3(NB), blk, 0, stream>>>(r, means, part2);
  k_final<<<dim3(1), blk, 0, stream>>>(part2, out);
}

// Round 2
// 1062.317 us; speedup vs baseline: 1.1827x; 1.1827x over previous
//
#include <hip/hip_runtime.h>
#include <math.h>

typedef unsigned int u32;
typedef unsigned long long u64;

#define N_ELEM 131072
#define NB 512                 // sort blocks per array (256 elems each)
#define BS 256
#define NP1 (N_ELEM + 1)       // 131073 prefix-sum points
#define CHUNK 513
#define NCH 256                // ceil(131073/513) = 256 exactly (last chunk: 258 pts)
#define HCAP 4096              // LDS merge capacity (vertices)

// ---- float <-> sortable key (ascending key order == descending float order) ----
__device__ __forceinline__ u32 f2key(float x) {
  u32 u = __float_as_uint(x);
  u32 t = (u & 0x80000000u) ? ~u : (u | 0x80000000u);
  return ~t;
}
__device__ __forceinline__ float key2f(u32 k) {
  u32 t = ~k;
  u32 u = (t & 0x80000000u) ? (t ^ 0x80000000u) : ~t;
  return __uint_as_float(u);
}

// ---------------- init: build keys + payload indices ----------------
__global__ void k_init(const float* in0, const float* in1, u32* keyA, u32* idxA) {
  int arr = blockIdx.y;
  int i = blockIdx.x * BS + threadIdx.x;
  const float* p = arr ? in1 : in0;
  keyA[arr * N_ELEM + i] = f2key(p[i]);
  idxA[arr * N_ELEM + i] = (u32)i;
}

// ---------------- radix pass: histogram ----------------
__global__ void k_hist(const u32* key, u32* gHist, int shift) {
  int arr = blockIdx.y, b = blockIdx.x, t = threadIdx.x;
  __shared__ u32 h[256];
  h[t] = 0;
  __syncthreads();
  u32 k = key[arr * N_ELEM + b * BS + t];
  atomicAdd(&h[(k >> shift) & 255u], 1u);
  __syncthreads();
  gHist[arr * (256 * NB) + t * NB + b] = h[t];
}

// ---------------- radix pass: exclusive scan of 256*NB entries ----------------
__global__ __launch_bounds__(1024) void k_scan(const u32* gHist, u32* gOfs) {
  int arr = blockIdx.x, t = threadIdx.x;
  const u32* h = gHist + arr * (256 * NB);
  u32* o = gOfs + arr * (256 * NB);
  u32 s = 0;
  for (int i = 0; i < 128; i++) s += h[t * 128 + i];
  __shared__ u32 sc[1024];
  sc[t] = s;
  __syncthreads();
  for (int off = 1; off < 1024; off <<= 1) {
    u32 v = (t >= off) ? sc[t - off] : 0u;
    __syncthreads();
    sc[t] += v;
    __syncthreads();
  }
  u32 run = (t == 0) ? 0u : sc[t - 1];
  for (int i = 0; i < 128; i++) {
    u32 x = h[t * 128 + i];
    o[t * 128 + i] = run;
    run += x;
  }
}

// ---------------- radix pass: stable scatter ----------------
__global__ void k_scatter(const u32* keyIn, const u32* idxIn, u32* keyOut, u32* idxOut,
                          const u32* gOfs, int shift) {
  int arr = blockIdx.y, b = blockIdx.x, t = threadIdx.x;
  int lane = t & 63, w = t >> 6;
  u32 k = keyIn[arr * N_ELEM + b * BS + t];
  u32 id = idxIn[arr * N_ELEM + b * BS + t];
  u32 d = (k >> shift) & 255u;
  u64 same = ~0ull;
#pragma unroll
  for (int bit = 0; bit < 8; bit++) {
    u64 bal = __ballot((d >> bit) & 1u);
    same &= ((d >> bit) & 1u) ? bal : ~bal;
  }
  u64 below = (1ull << lane) - 1ull;
  int wrank = __popcll(same & below);
  __shared__ u32 wh[4][256];
  wh[0][t] = 0; wh[1][t] = 0; wh[2][t] = 0; wh[3][t] = 0;
  __syncthreads();
  if (wrank == 0) wh[w][d] = (u32)__popcll(same);
  __syncthreads();
  u32 off = 0;
  for (int w2 = 0; w2 < w; w2++) off += wh[w2][d];
  u32 pos = gOfs[arr * (256 * NB) + d * NB + b] + off + (u32)wrank;
  keyOut[arr * N_ELEM + pos] = k;
  idxOut[arr * N_ELEM + pos] = id;
}

// ---------------- prefix sum of y_i = s_i - (n-i), f64 ----------------
__global__ void k_prefix1(const u32* key, double* C, double* bsum) {
  int arr = blockIdx.y, b = blockIdx.x, t = threadIdx.x;
  int i = b * BS + t;
  float x = key2f(key[arr * N_ELEM + i]);
  double y = (double)x / 0.1 - (double)(N_ELEM - i);
  __shared__ double sc[BS];
  sc[t] = y;
  __syncthreads();
  for (int off = 1; off < BS; off <<= 1) {
    double v = (t >= off) ? sc[t - off] : 0.0;
    __syncthreads();
    sc[t] += v;
    __syncthreads();
  }
  C[arr * NP1 + i + 1] = sc[t];
  if (t == BS - 1) bsum[arr * NB + b] = sc[t];
  if (b == 0 && t == 0) C[arr * NP1] = 0.0;
}

__global__ void k_prefix2(double* bsum) {
  int arr = blockIdx.x, t = threadIdx.x;  // NB threads
  __shared__ double sc[NB];
  sc[t] = bsum[arr * NB + t];
  __syncthreads();
  for (int off = 1; off < NB; off <<= 1) {
    double v = (t >= off) ? sc[t - off] : 0.0;
    __syncthreads();
    sc[t] += v;
    __syncthreads();
  }
  double e = (t == 0) ? 0.0 : sc[t - 1];
  bsum[arr * NB + t] = e;
}

__global__ void k_prefix3(double* C, const double* bsum) {
  int arr = blockIdx.y, b = blockIdx.x, t = threadIdx.x;
  int i = b * BS + t;
  C[arr * NP1 + i + 1] += bsum[arr * NB + b];
}

// ---------------- upper hull level 1: one thread per 513-pt chunk ----------------
// Stack top (indices aX,bX and C-values cA,cB) is register-cached: the cross-
// product test touches memory only on pops below depth 2 (rare). Point loads
// are 16-batched into registers -> ~33 memory round-trips per chunk.
__global__ __launch_bounds__(256) void k_hull1(const double* C, int* hullX, int* hullCnt) {
  int arr = blockIdx.x;
  int c = threadIdx.x;  // NCH == 256 == blockDim
  const double* Ca = C + (size_t)arr * NP1;
  int* st = hullX + ((size_t)arr * NCH + c) * CHUNK;
  int base = c * CHUNK;
  int end = base + CHUNK; if (end > NP1) end = NP1;
  int top = 0, aX = 0, bX = 0;
  double cA = 0.0, cB = 0.0;
  for (int i0 = base; i0 < end; i0 += 16) {
    double v[16];
#pragma unroll
    for (int j = 0; j < 16; j++) {
      int i = i0 + j;
      v[j] = (i < end) ? Ca[i] : 0.0;
    }
#pragma unroll
    for (int j = 0; j < 16; j++) {
      int i = i0 + j;
      if (i < end) {
        double Ci = v[j];
        while (top >= 2) {
          double cr = (double)(bX - aX) * (Ci - cA) - (cB - cA) * (double)(i - aX);
          if (cr >= 0.0) {  // bX on/below chord aX->i : pop
            top--;
            bX = aX; cB = cA;
            if (top >= 2) { aX = st[top - 2]; cA = Ca[aX]; }
          } else break;
        }
        st[top] = i;
        aX = bX; cA = cB;
        bX = i;  cB = Ci;
        top++;
      }
    }
  }
  hullCnt[arr * NCH + c] = top;
}

// ---------------- compact chunk-hull vertices into contiguous (x, C) arrays ----------------
__global__ __launch_bounds__(256) void k_compact(const double* C, const int* hullX,
                                                 const int* hullCnt, int* cvx, double* cvc,
                                                 int* tot) {
  int arr = blockIdx.x, t = threadIdx.x;  // one thread per chunk
  __shared__ int sc[NCH];
  int cnt = hullCnt[arr * NCH + t];
  sc[t] = cnt;
  __syncthreads();
  for (int off = 1; off < NCH; off <<= 1) {
    int v = (t >= off) ? sc[t - off] : 0;
    __syncthreads();
    sc[t] += v;
    __syncthreads();
  }
  int ofs = sc[t] - cnt;  // exclusive
  if (t == NCH - 1) tot[arr] = sc[t];
  const double* Ca = C + (size_t)arr * NP1;
  const int* st = hullX + ((size_t)arr * NCH + t) * CHUNK;
  int* ox = cvx + (size_t)arr * NP1;
  double* oc = cvc + (size_t)arr * NP1;
  for (int k = 0; k < cnt; k++) {
    int i = st[k];
    ox[ofs + k] = i;
    oc[ofs + k] = Ca[i];
  }
}

// ---------------- hull level 2: LDS-resident in-place merge ----------------
__global__ __launch_bounds__(256) void k_hull2(const int* cvx, const double* cvc,
                                               const int* tot_, int* fhX, int* fhCnt,
                                               double* stC) {
  int arr = blockIdx.x, t = threadIdx.x;
  int tot = tot_[arr];
  int* out = fhX + (size_t)arr * NP1;
  if (tot <= HCAP) {
    __shared__ int lx[HCAP];
    __shared__ double lc[HCAP];
    __shared__ int stop_;
    for (int k = t; k < tot; k += 256) {
      lx[k] = cvx[(size_t)arr * NP1 + k];
      lc[k] = cvc[(size_t)arr * NP1 + k];
    }
    __syncthreads();
    if (t == 0) {
      // in-place monotone chain: stack occupies lx/lc[0..top), top <= input pos
      int top = 0, aX = 0, bX = 0;
      double cA = 0.0, cB = 0.0;
      for (int k0 = 0; k0 < tot; k0 += 16) {
        int xr[16];
        double cv[16];
#pragma unroll
        for (int j = 0; j < 16; j++) {
          int k = k0 + j;
          if (k < tot) { xr[j] = lx[k]; cv[j] = lc[k]; }
        }
#pragma unroll
        for (int j = 0; j < 16; j++) {
          int k = k0 + j;
          if (k < tot) {
            int i = xr[j];
            double Ci = cv[j];
            while (top >= 2) {
              double cr = (double)(bX - aX) * (Ci - cA) - (cB - cA) * (double)(i - aX);
              if (cr >= 0.0) {
                top--;
                bX = aX; cB = cA;
                if (top >= 2) { aX = lx[top - 2]; cA = lc[top - 2]; }
              } else break;
            }
            lx[top] = i; lc[top] = Ci;
            aX = bX; cA = cB;
            bX = i;  cB = Ci;
            top++;
          }
        }
      }
      stop_ = top;
    }
    __syncthreads();
    int top = stop_;
    for (int k = t; k < top; k += 256) out[k] = lx[k];
    if (t == 0) fhCnt[arr] = top;
  } else {
    // fallback: serial global-memory merge (never hit for this data)
    if (t != 0) return;
    double* sC = stC + (size_t)arr * NP1;
    int top = 0, aX = 0, bX = 0;
    double cA = 0.0, cB = 0.0;
    for (int k = 0; k < tot; k++) {
      int i = cvx[(size_t)arr * NP1 + k];
      double Ci = cvc[(size_t)arr * NP1 + k];
      while (top >= 2) {
        double cr = (double)(bX - aX) * (Ci - cA) - (cB - cA) * (double)(i - aX);
        if (cr >= 0.0) {
          top--;
          bX = aX; cB = cA;
          if (top >= 2) { aX = out[top - 2]; cA = sC[top - 2]; }
        } else break;
      }
      out[top] = i; sC[top] = Ci;
      aX = bX; cA = cB;
      bX = i;  cB = Ci;
      top++;
    }
    fhCnt[arr] = top;
  }
}

// ---------------- expand hull slopes -> primal ranks, scatter to original order ----------------
__global__ void k_expand(const u32* key, const u32* idx, const double* C,
                         const int* fhX, const int* fhCnt, double* r) {
  int arr = blockIdx.y, b = blockIdx.x, t = threadIdx.x;
  int i = b * BS + t;
  const int* fx = fhX + (size_t)arr * NP1;
  int H = fhCnt[arr];
  int lo = 0, hi = H - 1;
  while (hi - lo > 1) {
    int mid = (lo + hi) >> 1;
    if (fx[mid] <= i) lo = mid; else hi = mid;
  }
  const double* Ca = C + (size_t)arr * NP1;
  int a = fx[lo], bb = fx[lo + 1];
  double v = (Ca[bb] - Ca[a]) / (double)(bb - a);
  double s = (double)key2f(key[arr * N_ELEM + i]) / 0.1;
  r[arr * N_ELEM + idx[arr * N_ELEM + i]] = s - v;
}

// ---------------- centered moments (analytic mean: permutahedron projection
// preserves coordinate sum -> mean(rank) == (N+1)/2 exactly) ----------------
__global__ void k_mom(const double* r, double* part2) {
  int b = blockIdx.x, t = threadIdx.x;
  int i = b * BS + t;
  const double m = 0.5 * (double)(N_ELEM + 1);  // 65536.5
  double a = r[i] - m;
  double c = r[N_ELEM + i] - m;
  __shared__ double s0[BS], s1[BS], s2[BS];
  s0[t] = a * c;
  s1[t] = a * a;
  s2[t] = c * c;
  __syncthreads();
  for (int off = BS / 2; off > 0; off >>= 1) {
    if (t < off) { s0[t] += s0[t + off]; s1[t] += s1[t + off]; s2[t] += s2[t + off]; }
    __syncthreads();
  }
  if (t == 0) {
    part2[b] = s0[0];
    part2[NB + b] = s1[0];
    part2[2 * NB + b] = s2[0];
  }
}

__global__ void k_final(const double* part2, float* out) {
  int t = threadIdx.x;
  __shared__ double s0[BS], s1[BS], s2[BS];
  s0[t] = part2[t] + part2[t + BS];
  s1[t] = part2[NB + t] + part2[NB + t + BS];
  s2[t] = part2[2 * NB + t] + part2[2 * NB + t + BS];
  __syncthreads();
  for (int off = BS / 2; off > 0; off >>= 1) {
    if (t < off) { s0[t] += s0[t + off]; s1[t] += s1[t + off]; s2[t] += s2[t + off]; }
    __syncthreads();
  }
  if (t == 0) out[0] = (float)(s0[0] / (sqrt(s1[0]) * sqrt(s2[0])));
}

// ---------------- host ----------------
extern "C" void kernel_launch(void* const* d_in, const int* in_sizes, int n_in,
                              void* d_out, int out_size, void* d_ws, size_t ws_size,
                              hipStream_t stream) {
  const float* in0 = (const float*)d_in[0];
  const float* in1 = (const float*)d_in[1];
  float* out = (float*)d_out;

  size_t off = 0;
  char* base = (char*)d_ws;
  auto alloc = [&](size_t bytes) -> char* {
    char* p = base + off;
    off += (bytes + 63) & ~(size_t)63;
    return p;
  };
  u32* keyA    = (u32*)alloc(sizeof(u32) * 2 * N_ELEM);
  u32* keyB    = (u32*)alloc(sizeof(u32) * 2 * N_ELEM);
  u32* idxA    = (u32*)alloc(sizeof(u32) * 2 * N_ELEM);
  u32* idxB    = (u32*)alloc(sizeof(u32) * 2 * N_ELEM);
  u32* gHist   = (u32*)alloc(sizeof(u32) * 2 * 256 * NB);
  u32* gOfs    = (u32*)alloc(sizeof(u32) * 2 * 256 * NB);
  double* C    = (double*)alloc(sizeof(double) * 2 * NP1);
  double* bsum = (double*)alloc(sizeof(double) * 2 * NB);
  int* hullX   = (int*)alloc(sizeof(int) * 2 * NCH * CHUNK);
  int* hullCnt = (int*)alloc(sizeof(int) * 2 * NCH);
  int* cvx     = (int*)alloc(sizeof(int) * 2 * NP1);
  double* cvc  = (double*)alloc(sizeof(double) * 2 * NP1);
  int* totv    = (int*)alloc(sizeof(int) * 2);
  int* fhX     = (int*)alloc(sizeof(int) * 2 * NP1);
  int* fhCnt   = (int*)alloc(sizeof(int) * 2);
  double* stC  = (double*)alloc(sizeof(double) * 2 * NP1);
  double* r    = (double*)alloc(sizeof(double) * 2 * N_ELEM);
  double* part2 = (double*)alloc(sizeof(double) * 3 * NB);
  (void)ws_size; (void)in_sizes; (void)n_in; (void)out_size;

  dim3 g2(NB, 2), blk(BS);

  k_init<<<g2, blk, 0, stream>>>(in0, in1, keyA, idxA);

  u32 *kin = keyA, *iin = idxA, *kout = keyB, *iout = idxB;
  for (int p = 0; p < 4; p++) {
    k_hist<<<g2, blk, 0, stream>>>(kin, gHist, p * 8);
    k_scan<<<dim3(2), dim3(1024), 0, stream>>>(gHist, gOfs);
    k_scatter<<<g2, blk, 0, stream>>>(kin, iin, kout, iout, gOfs, p * 8);
    u32* tk = kin; kin = kout; kout = tk;
    u32* ti = iin; iin = iout; iout = ti;
  }

  k_prefix1<<<g2, blk, 0, stream>>>(kin, C, bsum);
  k_prefix2<<<dim3(2), dim3(NB), 0, stream>>>(bsum);
  k_prefix3<<<g2, blk, 0, stream>>>(C, bsum);

  k_hull1<<<dim3(2), dim3(256), 0, stream>>>(C, hullX, hullCnt);
  k_compact<<<dim3(2), dim3(256), 0, stream>>>(C, hullX, hullCnt, cvx, cvc, totv);
  k_hull2<<<dim3(2), dim3(256), 0, stream>>>(cvx, cvc, totv, fhX, fhCnt, stC);

  k_expand<<<g2, blk, 0, stream>>>(kin, iin, C, fhX, fhCnt, r);

  k_mom<<<dim3(NB), blk, 0, stream>>>(r, part2);
  k_final<<<dim3(1), blk, 0, stream>>>(part2, out);
}

// Round 3
// 328.351 us; speedup vs baseline: 3.8263x; 3.2353x over previous
//
#include <hip/hip_runtime.h>
#include <math.h>

typedef unsigned int u32;
typedef unsigned long long u64;

#define N_ELEM 131072
#define NB 512                 // sort blocks per array (256 elems each)
#define BS 256
#define NP1 (N_ELEM + 1)       // 131073 prefix-sum points
#define HCAP 4096              // LDS merge capacity (vertices)

// ---- float <-> sortable key (ascending key order == descending float order) ----
__device__ __forceinline__ u32 f2key(float x) {
  u32 u = __float_as_uint(x);
  u32 t = (u & 0x80000000u) ? ~u : (u | 0x80000000u);
  return ~t;
}
__device__ __forceinline__ float key2f(u32 k) {
  u32 t = ~k;
  u32 u = (t & 0x80000000u) ? (t ^ 0x80000000u) : ~t;
  return __uint_as_float(u);
}

// candidate test for point p (1..N): can p be an upper-hull vertex?
// Necessary condition: C locally strictly concave at p  <=>  sorted-value gap
// s_{p-1} - s_p > reg. Slack 1e-9 makes the filter conservative (over-include);
// the exact C-f64 monotone chain in k_hull2 discards any false positives.
__device__ __forceinline__ int cand_flag(const u32* key, int arr, int p) {
  if (p >= N_ELEM) return 1;  // right endpoint always kept
  float a = key2f(key[arr * N_ELEM + p - 1]);
  float c = key2f(key[arr * N_ELEM + p]);
  return ((double)a - (double)c > 0.1 * (1.0 - 1e-9)) ? 1 : 0;
}

// ---------------- init: build keys + payload indices ----------------
__global__ void k_init(const float* in0, const float* in1, u32* keyA, u32* idxA) {
  int arr = blockIdx.y;
  int i = blockIdx.x * BS + threadIdx.x;
  const float* p = arr ? in1 : in0;
  keyA[arr * N_ELEM + i] = f2key(p[i]);
  idxA[arr * N_ELEM + i] = (u32)i;
}

// ---------------- radix pass: histogram ----------------
__global__ void k_hist(const u32* key, u32* gHist, int shift) {
  int arr = blockIdx.y, b = blockIdx.x, t = threadIdx.x;
  __shared__ u32 h[256];
  h[t] = 0;
  __syncthreads();
  u32 k = key[arr * N_ELEM + b * BS + t];
  atomicAdd(&h[(k >> shift) & 255u], 1u);
  __syncthreads();
  gHist[arr * (256 * NB) + t * NB + b] = h[t];
}

// ---------------- radix pass: exclusive scan of 256*NB entries ----------------
// Two-pass uint4: pass1 sums 32 vec4 per thread (registers stay low), LDS scan,
// pass2 re-reads (L2-hot) and writes running offsets as vec4.
__global__ __launch_bounds__(1024) void k_scan(const u32* gHist, u32* gOfs) {
  int arr = blockIdx.x, t = threadIdx.x;
  const uint4* h4 = (const uint4*)(gHist + (size_t)arr * (256 * NB));
  uint4* o4 = (uint4*)(gOfs + (size_t)arr * (256 * NB));
  u32 s = 0;
#pragma unroll 4
  for (int i = 0; i < 32; i++) {
    uint4 v = h4[t * 32 + i];
    s += v.x + v.y + v.z + v.w;
  }
  __shared__ u32 sc[1024];
  sc[t] = s;
  __syncthreads();
  for (int off = 1; off < 1024; off <<= 1) {
    u32 v = (t >= off) ? sc[t - off] : 0u;
    __syncthreads();
    sc[t] += v;
    __syncthreads();
  }
  u32 run = (t == 0) ? 0u : sc[t - 1];
#pragma unroll 4
  for (int i = 0; i < 32; i++) {
    uint4 v = h4[t * 32 + i];
    uint4 w;
    w.x = run; run += v.x;
    w.y = run; run += v.y;
    w.z = run; run += v.z;
    w.w = run; run += v.w;
    o4[t * 32 + i] = w;
  }
}

// ---------------- radix pass: stable scatter ----------------
__global__ void k_scatter(const u32* keyIn, const u32* idxIn, u32* keyOut, u32* idxOut,
                          const u32* gOfs, int shift) {
  int arr = blockIdx.y, b = blockIdx.x, t = threadIdx.x;
  int lane = t & 63, w = t >> 6;
  u32 k = keyIn[arr * N_ELEM + b * BS + t];
  u32 id = idxIn[arr * N_ELEM + b * BS + t];
  u32 d = (k >> shift) & 255u;
  u64 same = ~0ull;
#pragma unroll
  for (int bit = 0; bit < 8; bit++) {
    u64 bal = __ballot((d >> bit) & 1u);
    same &= ((d >> bit) & 1u) ? bal : ~bal;
  }
  u64 below = (1ull << lane) - 1ull;
  int wrank = __popcll(same & below);
  __shared__ u32 wh[4][256];
  wh[0][t] = 0; wh[1][t] = 0; wh[2][t] = 0; wh[3][t] = 0;
  __syncthreads();
  if (wrank == 0) wh[w][d] = (u32)__popcll(same);
  __syncthreads();
  u32 off = 0;
  for (int w2 = 0; w2 < w; w2++) off += wh[w2][d];
  u32 pos = gOfs[arr * (256 * NB) + d * NB + b] + off + (u32)wrank;
  keyOut[arr * N_ELEM + pos] = k;
  idxOut[arr * N_ELEM + pos] = id;
}

// ---------------- prefix sum of y_i = s_i - (n-i), f64 ----------------
__global__ void k_prefix1(const u32* key, double* C, double* bsum) {
  int arr = blockIdx.y, b = blockIdx.x, t = threadIdx.x;
  int i = b * BS + t;
  float x = key2f(key[arr * N_ELEM + i]);
  double y = (double)x / 0.1 - (double)(N_ELEM - i);
  __shared__ double sc[BS];
  sc[t] = y;
  __syncthreads();
  for (int off = 1; off < BS; off <<= 1) {
    double v = (t >= off) ? sc[t - off] : 0.0;
    __syncthreads();
    sc[t] += v;
    __syncthreads();
  }
  C[arr * NP1 + i + 1] = sc[t];
  if (t == BS - 1) bsum[arr * NB + b] = sc[t];
  if (b == 0 && t == 0) C[arr * NP1] = 0.0;
}

__global__ void k_prefix2(double* bsum) {
  int arr = blockIdx.x, t = threadIdx.x;  // NB threads
  __shared__ double sc[NB];
  sc[t] = bsum[arr * NB + t];
  __syncthreads();
  for (int off = 1; off < NB; off <<= 1) {
    double v = (t >= off) ? sc[t - off] : 0.0;
    __syncthreads();
    sc[t] += v;
    __syncthreads();
  }
  double e = (t == 0) ? 0.0 : sc[t - 1];
  bsum[arr * NB + t] = e;
}

// fused: finish prefix sum + hull-candidate block counts
__global__ void k_prefix3(double* C, const double* bsum, const u32* key, int* candCnt) {
  int arr = blockIdx.y, b = blockIdx.x, t = threadIdx.x;
  int i = b * BS + t;
  C[arr * NP1 + i + 1] += bsum[arr * NB + b];
  int flag = cand_flag(key, arr, i + 1);
  __shared__ int sc[BS];
  sc[t] = flag;
  __syncthreads();
  for (int off = BS / 2; off > 0; off >>= 1) {
    if (t < off) sc[t] += sc[t + off];
    __syncthreads();
  }
  if (t == 0) candCnt[arr * NB + b] = sc[0];
}

// exclusive scan of per-block candidate counts (base offset 1 for point 0)
__global__ __launch_bounds__(NB) void k_candscan(int* candCnt, int* totv) {
  int arr = blockIdx.x, t = threadIdx.x;  // NB threads
  __shared__ int sc[NB];
  int v0 = candCnt[arr * NB + t];
  sc[t] = v0;
  __syncthreads();
  for (int off = 1; off < NB; off <<= 1) {
    int v = (t >= off) ? sc[t - off] : 0;
    __syncthreads();
    sc[t] += v;
    __syncthreads();
  }
  candCnt[arr * NB + t] = 1 + sc[t] - v0;  // exclusive + base 1
  if (t == NB - 1) totv[arr] = 1 + sc[t];
}

// ordered write of candidate (x, C[x]) pairs
__global__ void k_candwrite(const u32* key, const double* C, const int* candCnt,
                            int* cvx, double* cvc) {
  int arr = blockIdx.y, b = blockIdx.x, t = threadIdx.x;
  int p = b * BS + t + 1;
  int flag = cand_flag(key, arr, p);
  __shared__ int sc[BS];
  sc[t] = flag;
  __syncthreads();
  for (int off = 1; off < BS; off <<= 1) {
    int v = (t >= off) ? sc[t - off] : 0;
    __syncthreads();
    sc[t] += v;
    __syncthreads();
  }
  int* ox = cvx + (size_t)arr * NP1;
  double* oc = cvc + (size_t)arr * NP1;
  if (flag) {
    int pos = candCnt[arr * NB + b] + sc[t] - 1;
    ox[pos] = p;
    oc[pos] = C[arr * NP1 + p];
  }
  if (b == 0 && t == 0) { ox[0] = 0; oc[0] = 0.0; }
}

// ---------------- hull merge: LDS-resident monotone chain over candidates ----------------
__global__ __launch_bounds__(256) void k_hull2(const int* cvx, const double* cvc,
                                               const int* tot_, int* fhX, int* fhCnt,
                                               double* stC) {
  int arr = blockIdx.x, t = threadIdx.x;
  int tot = tot_[arr];
  int* out = fhX + (size_t)arr * NP1;
  if (tot <= HCAP) {
    __shared__ int lx[HCAP];
    __shared__ double lc[HCAP];
    __shared__ int stop_;
    for (int k = t; k < tot; k += 256) {
      lx[k] = cvx[(size_t)arr * NP1 + k];
      lc[k] = cvc[(size_t)arr * NP1 + k];
    }
    __syncthreads();
    if (t == 0) {
      int top = 0, aX = 0, bX = 0;
      double cA = 0.0, cB = 0.0;
      for (int k = 0; k < tot; k++) {
        int i = lx[k];
        double Ci = lc[k];
        while (top >= 2) {
          double cr = (double)(bX - aX) * (Ci - cA) - (cB - cA) * (double)(i - aX);
          if (cr >= 0.0) {  // bX on/below chord aX->i : pop
            top--;
            bX = aX; cB = cA;
            if (top >= 2) { aX = lx[top - 2]; cA = lc[top - 2]; }
          } else break;
        }
        lx[top] = i; lc[top] = Ci;
        aX = bX; cA = cB;
        bX = i;  cB = Ci;
        top++;
      }
      stop_ = top;
    }
    __syncthreads();
    int top = stop_;
    for (int k = t; k < top; k += 256) out[k] = lx[k];
    if (t == 0) fhCnt[arr] = top;
  } else {
    // fallback: serial global-memory merge (pathological inputs only)
    if (t != 0) return;
    double* sC = stC + (size_t)arr * NP1;
    int top = 0, aX = 0, bX = 0;
    double cA = 0.0, cB = 0.0;
    for (int k = 0; k < tot; k++) {
      int i = cvx[(size_t)arr * NP1 + k];
      double Ci = cvc[(size_t)arr * NP1 + k];
      while (top >= 2) {
        double cr = (double)(bX - aX) * (Ci - cA) - (cB - cA) * (double)(i - aX);
        if (cr >= 0.0) {
          top--;
          bX = aX; cB = cA;
          if (top >= 2) { aX = out[top - 2]; cA = sC[top - 2]; }
        } else break;
      }
      out[top] = i; sC[top] = Ci;
      aX = bX; cA = cB;
      bX = i;  cB = Ci;
      top++;
    }
    fhCnt[arr] = top;
  }
}

// ---------------- expand hull slopes -> primal ranks, scatter to original order ----------------
__global__ void k_expand(const u32* key, const u32* idx, const double* C,
                         const int* fhX, const int* fhCnt, double* r) {
  int arr = blockIdx.y, b = blockIdx.x, t = threadIdx.x;
  int i = b * BS + t;
  const int* fx = fhX + (size_t)arr * NP1;
  int H = fhCnt[arr];
  int lo = 0, hi = H - 1;
  while (hi - lo > 1) {
    int mid = (lo + hi) >> 1;
    if (fx[mid] <= i) lo = mid; else hi = mid;
  }
  const double* Ca = C + (size_t)arr * NP1;
  int a = fx[lo], bb = fx[lo + 1];
  double v = (Ca[bb] - Ca[a]) / (double)(bb - a);
  double s = (double)key2f(key[arr * N_ELEM + i]) / 0.1;
  r[arr * N_ELEM + idx[arr * N_ELEM + i]] = s - v;
}

// ---------------- centered moments (analytic mean: permutahedron projection
// preserves coordinate sum -> mean(rank) == (N+1)/2 exactly) ----------------
__global__ void k_mom(const double* r, double* part2) {
  int b = blockIdx.x, t = threadIdx.x;
  int i = b * BS + t;
  const double m = 0.5 * (double)(N_ELEM + 1);  // 65536.5
  double a = r[i] - m;
  double c = r[N_ELEM + i] - m;
  __shared__ double s0[BS], s1[BS], s2[BS];
  s0[t] = a * c;
  s1[t] = a * a;
  s2[t] = c * c;
  __syncthreads();
  for (int off = BS / 2; off > 0; off >>= 1) {
    if (t < off) { s0[t] += s0[t + off]; s1[t] += s1[t + off]; s2[t] += s2[t + off]; }
    __syncthreads();
  }
  if (t == 0) {
    part2[b] = s0[0];
    part2[NB + b] = s1[0];
    part2[2 * NB + b] = s2[0];
  }
}

__global__ void k_final(const double* part2, float* out) {
  int t = threadIdx.x;
  __shared__ double s0[BS], s1[BS], s2[BS];
  s0[t] = part2[t] + part2[t + BS];
  s1[t] = part2[NB + t] + part2[NB + t + BS];
  s2[t] = part2[2 * NB + t] + part2[2 * NB + t + BS];
  __syncthreads();
  for (int off = BS / 2; off > 0; off >>= 1) {
    if (t < off) { s0[t] += s0[t + off]; s1[t] += s1[t + off]; s2[t] += s2[t + off]; }
    __syncthreads();
  }
  if (t == 0) out[0] = (float)(s0[0] / (sqrt(s1[0]) * sqrt(s2[0])));
}

// ---------------- host ----------------
extern "C" void kernel_launch(void* const* d_in, const int* in_sizes, int n_in,
                              void* d_out, int out_size, void* d_ws, size_t ws_size,
                              hipStream_t stream) {
  const float* in0 = (const float*)d_in[0];
  const float* in1 = (const float*)d_in[1];
  float* out = (float*)d_out;

  size_t off = 0;
  char* base = (char*)d_ws;
  auto alloc = [&](size_t bytes) -> char* {
    char* p = base + off;
    off += (bytes + 63) & ~(size_t)63;
    return p;
  };
  u32* keyA    = (u32*)alloc(sizeof(u32) * 2 * N_ELEM);
  u32* keyB    = (u32*)alloc(sizeof(u32) * 2 * N_ELEM);
  u32* idxA    = (u32*)alloc(sizeof(u32) * 2 * N_ELEM);
  u32* idxB    = (u32*)alloc(sizeof(u32) * 2 * N_ELEM);
  u32* gHist   = (u32*)alloc(sizeof(u32) * 2 * 256 * NB);
  u32* gOfs    = (u32*)alloc(sizeof(u32) * 2 * 256 * NB);
  double* C    = (double*)alloc(sizeof(double) * 2 * NP1);
  double* bsum = (double*)alloc(sizeof(double) * 2 * NB);
  int* candCnt = (int*)alloc(sizeof(int) * 2 * NB);
  int* cvx     = (int*)alloc(sizeof(int) * 2 * NP1);
  double* cvc  = (double*)alloc(sizeof(double) * 2 * NP1);
  int* totv    = (int*)alloc(sizeof(int) * 2);
  int* fhX     = (int*)alloc(sizeof(int) * 2 * NP1);
  int* fhCnt   = (int*)alloc(sizeof(int) * 2);
  double* stC  = (double*)alloc(sizeof(double) * 2 * NP1);
  double* r    = (double*)alloc(sizeof(double) * 2 * N_ELEM);
  double* part2 = (double*)alloc(sizeof(double) * 3 * NB);
  (void)ws_size; (void)in_sizes; (void)n_in; (void)out_size;

  dim3 g2(NB, 2), blk(BS);

  k_init<<<g2, blk, 0, stream>>>(in0, in1, keyA, idxA);

  u32 *kin = keyA, *iin = idxA, *kout = keyB, *iout = idxB;
  for (int p = 0; p < 4; p++) {
    k_hist<<<g2, blk, 0, stream>>>(kin, gHist, p * 8);
    k_scan<<<dim3(2), dim3(1024), 0, stream>>>(gHist, gOfs);
    k_scatter<<<g2, blk, 0, stream>>>(kin, iin, kout, iout, gOfs, p * 8);
    u32* tk = kin; kin = kout; kout = tk;
    u32* ti = iin; iin = iout; iout = ti;
  }

  k_prefix1<<<g2, blk, 0, stream>>>(kin, C, bsum);
  k_prefix2<<<dim3(2), dim3(NB), 0, stream>>>(bsum);
  k_prefix3<<<g2, blk, 0, stream>>>(C, bsum, kin, candCnt);

  k_candscan<<<dim3(2), dim3(NB), 0, stream>>>(candCnt, totv);
  k_candwrite<<<g2, blk, 0, stream>>>(kin, C, candCnt, cvx, cvc);
  k_hull2<<<dim3(2), dim3(256), 0, stream>>>(cvx, cvc, totv, fhX, fhCnt, stC);

  k_expand<<<g2, blk, 0, stream>>>(kin, iin, C, fhX, fhCnt, r);

  k_mom<<<dim3(NB), blk, 0, stream>>>(r, part2);
  k_final<<<dim3(1), blk, 0, stream>>>(part2, out);
}

// Round 4
// 105.240 us; speedup vs baseline: 11.9381x; 3.1200x over previous
//
#include <hip/hip_runtime.h>
#include <math.h>

typedef unsigned int u32;
typedef unsigned long long u64;

#define N_ELEM 131072
#define NB 512                 // sort blocks per array (256 elems each)
#define BS 256
#define NP1 (N_ELEM + 1)       // 131073 prefix-sum points
#define NTILE 512              // scan tiles per array: 256*NB / 256
#define HCAP 4096              // LDS merge capacity (vertices)
#define HCAP2 1024             // LDS hull capacity in rankmom

// ---- float <-> sortable key (ascending key order == descending float order) ----
__device__ __forceinline__ u32 f2key(float x) {
  u32 u = __float_as_uint(x);
  u32 t = (u & 0x80000000u) ? ~u : (u | 0x80000000u);
  return ~t;
}
__device__ __forceinline__ float key2f(u32 k) {
  u32 t = ~k;
  u32 u = (t & 0x80000000u) ? (t ^ 0x80000000u) : ~t;
  return __uint_as_float(u);
}

// candidate test for point p (1..N): can p be an upper-hull vertex?
// Necessary condition: C locally strictly concave at p <=> sorted-value gap
// s_{p-1} - s_p > reg. Slack makes the filter conservative (over-include);
// the exact C-f64 monotone chain in k_hull2 discards false positives.
__device__ __forceinline__ int cand_flag(const u32* key, int arr, int p) {
  if (p >= N_ELEM) return 1;  // right endpoint always kept
  float a = key2f(key[arr * N_ELEM + p - 1]);
  float c = key2f(key[arr * N_ELEM + p]);
  return ((double)a - (double)c > 0.1 * (1.0 - 1e-9)) ? 1 : 0;
}

// ---------------- radix pass: histogram ----------------
template <bool FIRST>
__global__ void k_hist(const float* in0, const float* in1, const u32* keyIn,
                       u32* gHist, int shift) {
  int arr = blockIdx.y, b = blockIdx.x, t = threadIdx.x;
  __shared__ u32 h[256];
  h[t] = 0;
  __syncthreads();
  u32 k;
  if (FIRST) {
    const float* p = arr ? in1 : in0;
    k = f2key(p[b * BS + t]);
  } else {
    k = keyIn[arr * N_ELEM + b * BS + t];
  }
  atomicAdd(&h[(k >> shift) & 255u], 1u);
  __syncthreads();
  gHist[arr * (256 * NB) + t * NB + b] = h[t];  // digit-major: entry = d*NB + b
}

// ---------------- hierarchical scan: tile-local exclusive scan + tile sums ----------------
__global__ void k_scan1(const u32* gHist, u32* gOfs, u32* tileSum) {
  int arr = blockIdx.y, blk = blockIdx.x, t = threadIdx.x;
  int e = blk * BS + t;
  u32 v0 = gHist[arr * (256 * NB) + e];
  __shared__ u32 sc[BS];
  sc[t] = v0;
  __syncthreads();
  for (int off = 1; off < BS; off <<= 1) {
    u32 v = (t >= off) ? sc[t - off] : 0u;
    __syncthreads();
    sc[t] += v;
    __syncthreads();
  }
  gOfs[arr * (256 * NB) + e] = sc[t] - v0;  // exclusive within tile
  if (t == BS - 1) tileSum[arr * NTILE + blk] = sc[t];
}

__global__ __launch_bounds__(NTILE) void k_scan2(u32* tileSum) {
  int arr = blockIdx.x, t = threadIdx.x;  // NTILE threads
  u32 v0 = tileSum[arr * NTILE + t];
  __shared__ u32 sc[NTILE];
  sc[t] = v0;
  __syncthreads();
  for (int off = 1; off < NTILE; off <<= 1) {
    u32 v = (t >= off) ? sc[t - off] : 0u;
    __syncthreads();
    sc[t] += v;
    __syncthreads();
  }
  tileSum[arr * NTILE + t] = sc[t] - v0;  // exclusive across tiles
}

// ---------------- radix pass: stable scatter (keys only, tile offset fused) ----------------
template <bool FIRST>
__global__ void k_scatter(const float* in0, const float* in1, const u32* keyIn,
                          u32* keyOut, const u32* gOfs, const u32* tileSum, int shift) {
  int arr = blockIdx.y, b = blockIdx.x, t = threadIdx.x;
  int lane = t & 63, w = t >> 6;
  u32 k;
  if (FIRST) {
    const float* p = arr ? in1 : in0;
    k = f2key(p[b * BS + t]);
  } else {
    k = keyIn[arr * N_ELEM + b * BS + t];
  }
  u32 d = (k >> shift) & 255u;
  u64 same = ~0ull;
#pragma unroll
  for (int bit = 0; bit < 8; bit++) {
    u64 bal = __ballot((d >> bit) & 1u);
    same &= ((d >> bit) & 1u) ? bal : ~bal;
  }
  u64 below = (1ull << lane) - 1ull;
  int wrank = __popcll(same & below);
  __shared__ u32 wh[4][256];
  wh[0][t] = 0; wh[1][t] = 0; wh[2][t] = 0; wh[3][t] = 0;
  __syncthreads();
  if (wrank == 0) wh[w][d] = (u32)__popcll(same);
  __syncthreads();
  u32 off = 0;
  for (int w2 = 0; w2 < w; w2++) off += wh[w2][d];
  u32 e = d * NB + (u32)b;
  u32 pos = gOfs[arr * (256 * NB) + e] + tileSum[arr * NTILE + (e >> 8)] + off + (u32)wrank;
  keyOut[arr * N_ELEM + pos] = k;
}

// ---------------- prefix sum of y_i = s_i - (n-i), f64 ----------------
__global__ void k_prefix1(const u32* key, double* C, double* bsum) {
  int arr = blockIdx.y, b = blockIdx.x, t = threadIdx.x;
  int i = b * BS + t;
  float x = key2f(key[arr * N_ELEM + i]);
  double y = (double)x / 0.1 - (double)(N_ELEM - i);
  __shared__ double sc[BS];
  sc[t] = y;
  __syncthreads();
  for (int off = 1; off < BS; off <<= 1) {
    double v = (t >= off) ? sc[t - off] : 0.0;
    __syncthreads();
    sc[t] += v;
    __syncthreads();
  }
  C[arr * NP1 + i + 1] = sc[t];
  if (t == BS - 1) bsum[arr * NB + b] = sc[t];
  if (b == 0 && t == 0) C[arr * NP1] = 0.0;
}

__global__ __launch_bounds__(NB) void k_prefix2(double* bsum) {
  int arr = blockIdx.x, t = threadIdx.x;  // NB threads
  __shared__ double sc[NB];
  sc[t] = bsum[arr * NB + t];
  __syncthreads();
  for (int off = 1; off < NB; off <<= 1) {
    double v = (t >= off) ? sc[t - off] : 0.0;
    __syncthreads();
    sc[t] += v;
    __syncthreads();
  }
  double e = (t == 0) ? 0.0 : sc[t - 1];
  bsum[arr * NB + t] = e;
}

// fused: finish prefix sum + hull-candidate block counts
__global__ void k_prefix3(double* C, const double* bsum, const u32* key, int* candCnt) {
  int arr = blockIdx.y, b = blockIdx.x, t = threadIdx.x;
  int i = b * BS + t;
  C[arr * NP1 + i + 1] += bsum[arr * NB + b];
  int flag = cand_flag(key, arr, i + 1);
  __shared__ int sc[BS];
  sc[t] = flag;
  __syncthreads();
  for (int off = BS / 2; off > 0; off >>= 1) {
    if (t < off) sc[t] += sc[t + off];
    __syncthreads();
  }
  if (t == 0) candCnt[arr * NB + b] = sc[0];
}

// exclusive scan of per-block candidate counts (base offset 1 for point 0)
__global__ __launch_bounds__(NB) void k_candscan(int* candCnt, int* totv) {
  int arr = blockIdx.x, t = threadIdx.x;  // NB threads
  __shared__ int sc[NB];
  int v0 = candCnt[arr * NB + t];
  sc[t] = v0;
  __syncthreads();
  for (int off = 1; off < NB; off <<= 1) {
    int v = (t >= off) ? sc[t - off] : 0;
    __syncthreads();
    sc[t] += v;
    __syncthreads();
  }
  candCnt[arr * NB + t] = 1 + sc[t] - v0;  // exclusive + base 1
  if (t == NB - 1) totv[arr] = 1 + sc[t];
}

// ordered write of candidate (x, C[x]) pairs
__global__ void k_candwrite(const u32* key, const double* C, const int* candCnt,
                            int* cvx, double* cvc) {
  int arr = blockIdx.y, b = blockIdx.x, t = threadIdx.x;
  int p = b * BS + t + 1;
  int flag = cand_flag(key, arr, p);
  __shared__ int sc[BS];
  sc[t] = flag;
  __syncthreads();
  for (int off = 1; off < BS; off <<= 1) {
    int v = (t >= off) ? sc[t - off] : 0;
    __syncthreads();
    sc[t] += v;
    __syncthreads();
  }
  int* ox = cvx + (size_t)arr * NP1;
  double* oc = cvc + (size_t)arr * NP1;
  if (flag) {
    int pos = candCnt[arr * NB + b] + sc[t] - 1;
    ox[pos] = p;
    oc[pos] = C[arr * NP1 + p];
  }
  if (b == 0 && t == 0) { ox[0] = 0; oc[0] = 0.0; }
}

// ---------------- hull merge: LDS-resident monotone chain over candidates ----------------
// Also emits per-segment slopes fhS[k] = (C[x_{k+1}]-C[x_k])/(x_{k+1}-x_k).
__global__ __launch_bounds__(256) void k_hull2(const int* cvx, const double* cvc,
                                               const int* tot_, int* fhX, double* fhS,
                                               int* fhCnt, double* stC) {
  int arr = blockIdx.x, t = threadIdx.x;
  int tot = tot_[arr];
  int* out = fhX + (size_t)arr * NP1;
  double* os = fhS + (size_t)arr * NP1;
  if (tot <= HCAP) {
    __shared__ int lx[HCAP];
    __shared__ double lc[HCAP];
    __shared__ int stop_;
    for (int k = t; k < tot; k += 256) {
      lx[k] = cvx[(size_t)arr * NP1 + k];
      lc[k] = cvc[(size_t)arr * NP1 + k];
    }
    __syncthreads();
    if (t == 0) {
      int top = 0, aX = 0, bX = 0;
      double cA = 0.0, cB = 0.0;
      for (int k = 0; k < tot; k++) {
        int i = lx[k];
        double Ci = lc[k];
        while (top >= 2) {
          double cr = (double)(bX - aX) * (Ci - cA) - (cB - cA) * (double)(i - aX);
          if (cr >= 0.0) {  // bX on/below chord aX->i : pop
            top--;
            bX = aX; cB = cA;
            if (top >= 2) { aX = lx[top - 2]; cA = lc[top - 2]; }
          } else break;
        }
        lx[top] = i; lc[top] = Ci;
        aX = bX; cA = cB;
        bX = i;  cB = Ci;
        top++;
      }
      stop_ = top;
    }
    __syncthreads();
    int top = stop_;
    for (int k = t; k < top; k += 256) out[k] = lx[k];
    for (int k = t; k < top - 1; k += 256)
      os[k] = (lc[k + 1] - lc[k]) / (double)(lx[k + 1] - lx[k]);
    if (t == 0) fhCnt[arr] = top;
  } else {
    // fallback: serial global-memory merge (pathological inputs only)
    if (t != 0) return;
    double* sC = stC + (size_t)arr * NP1;
    int top = 0, aX = 0, bX = 0;
    double cA = 0.0, cB = 0.0;
    for (int k = 0; k < tot; k++) {
      int i = cvx[(size_t)arr * NP1 + k];
      double Ci = cvc[(size_t)arr * NP1 + k];
      while (top >= 2) {
        double cr = (double)(bX - aX) * (Ci - cA) - (cB - cA) * (double)(i - aX);
        if (cr >= 0.0) {
          top--;
          bX = aX; cB = cA;
          if (top >= 2) { aX = out[top - 2]; cA = sC[top - 2]; }
        } else break;
      }
      out[top] = i; sC[top] = Ci;
      aX = bX; cA = cB;
      bX = i;  cB = Ci;
      top++;
    }
    for (int k = 0; k < top - 1; k++)
      os[k] = (sC[k + 1] - sC[k]) / (double)(out[k + 1] - out[k]);
    fhCnt[arr] = top;
  }
}

// ---------------- fused rank + centered moments ----------------
// Rank of original element i: its key's position p in the sorted keys (exact
// duplicates share gap 0 < reg -> same pool -> identical soft-rank, so any
// matching position is valid), rank = x/reg - slope(segment containing p).
// Mean is analytic: permutahedron projection preserves coordinate sum ->
// mean(rank) == (N+1)/2 exactly.
__device__ __forceinline__ int lb_u32(const u32* a, u32 key) {
  int lo = 0, hi = N_ELEM;
  while (lo < hi) {
    int mid = (lo + hi) >> 1;
    if (a[mid] < key) lo = mid + 1; else hi = mid;
  }
  return lo;
}

__global__ __launch_bounds__(256) void k_rankmom(const float* in0, const float* in1,
                                                 const u32* sorted, const int* fhX,
                                                 const double* fhS, const int* fhCnt,
                                                 double* part2) {
  int b = blockIdx.x, t = threadIdx.x;
  __shared__ int lx0[HCAP2], lx1[HCAP2];
  __shared__ double ls0[HCAP2], ls1[HCAP2];
  int H0 = fhCnt[0], H1 = fhCnt[1];
  bool f0 = (H0 <= HCAP2), f1 = (H1 <= HCAP2);
  if (f0) for (int k = t; k < H0; k += 256) {
    lx0[k] = fhX[k];
    if (k < H0 - 1) ls0[k] = fhS[k];
  }
  if (f1) for (int k = t; k < H1; k += 256) {
    lx1[k] = fhX[NP1 + k];
    if (k < H1 - 1) ls1[k] = fhS[NP1 + k];
  }
  __syncthreads();
  int i = b * BS + t;
  float x0 = in0[i], x1 = in1[i];
  int p0 = lb_u32(sorted, f2key(x0));
  int p1 = lb_u32(sorted + N_ELEM, f2key(x1));
  double v0, v1;
  if (f0) {
    int lo = 0, hi = H0 - 1;
    while (hi - lo > 1) { int mid = (lo + hi) >> 1; if (lx0[mid] <= p0) lo = mid; else hi = mid; }
    v0 = ls0[lo];
  } else {
    int lo = 0, hi = H0 - 1;
    while (hi - lo > 1) { int mid = (lo + hi) >> 1; if (fhX[mid] <= p0) lo = mid; else hi = mid; }
    v0 = fhS[lo];
  }
  if (f1) {
    int lo = 0, hi = H1 - 1;
    while (hi - lo > 1) { int mid = (lo + hi) >> 1; if (lx1[mid] <= p1) lo = mid; else hi = mid; }
    v1 = ls1[lo];
  } else {
    int lo = 0, hi = H1 - 1;
    while (hi - lo > 1) { int mid = (lo + hi) >> 1; if (fhX[NP1 + mid] <= p1) lo = mid; else hi = mid; }
    v1 = fhS[NP1 + lo];
  }
  const double m = 0.5 * (double)(N_ELEM + 1);  // 65536.5
  double a = (double)x0 / 0.1 - v0 - m;
  double c = (double)x1 / 0.1 - v1 - m;
  __shared__ double s0[BS], s1[BS], s2[BS];
  s0[t] = a * c;
  s1[t] = a * a;
  s2[t] = c * c;
  __syncthreads();
  for (int off = BS / 2; off > 0; off >>= 1) {
    if (t < off) { s0[t] += s0[t + off]; s1[t] += s1[t + off]; s2[t] += s2[t + off]; }
    __syncthreads();
  }
  if (t == 0) {
    part2[b] = s0[0];
    part2[NB + b] = s1[0];
    part2[2 * NB + b] = s2[0];
  }
}

__global__ void k_final(const double* part2, float* out) {
  int t = threadIdx.x;
  __shared__ double s0[BS], s1[BS], s2[BS];
  s0[t] = part2[t] + part2[t + BS];
  s1[t] = part2[NB + t] + part2[NB + t + BS];
  s2[t] = part2[2 * NB + t] + part2[2 * NB + t + BS];
  __syncthreads();
  for (int off = BS / 2; off > 0; off >>= 1) {
    if (t < off) { s0[t] += s0[t + off]; s1[t] += s1[t + off]; s2[t] += s2[t + off]; }
    __syncthreads();
  }
  if (t == 0) out[0] = (float)(s0[0] / (sqrt(s1[0]) * sqrt(s2[0])));
}

// ---------------- host ----------------
extern "C" void kernel_launch(void* const* d_in, const int* in_sizes, int n_in,
                              void* d_out, int out_size, void* d_ws, size_t ws_size,
                              hipStream_t stream) {
  const float* in0 = (const float*)d_in[0];
  const float* in1 = (const float*)d_in[1];
  float* out = (float*)d_out;

  size_t off = 0;
  char* base = (char*)d_ws;
  auto alloc = [&](size_t bytes) -> char* {
    char* p = base + off;
    off += (bytes + 63) & ~(size_t)63;
    return p;
  };
  u32* keyA    = (u32*)alloc(sizeof(u32) * 2 * N_ELEM);
  u32* keyB    = (u32*)alloc(sizeof(u32) * 2 * N_ELEM);
  u32* gHist   = (u32*)alloc(sizeof(u32) * 2 * 256 * NB);
  u32* gOfs    = (u32*)alloc(sizeof(u32) * 2 * 256 * NB);
  u32* tileSum = (u32*)alloc(sizeof(u32) * 2 * NTILE);
  double* C    = (double*)alloc(sizeof(double) * 2 * NP1);
  double* bsum = (double*)alloc(sizeof(double) * 2 * NB);
  int* candCnt = (int*)alloc(sizeof(int) * 2 * NB);
  int* cvx     = (int*)alloc(sizeof(int) * 2 * NP1);
  double* cvc  = (double*)alloc(sizeof(double) * 2 * NP1);
  int* totv    = (int*)alloc(sizeof(int) * 2);
  int* fhX     = (int*)alloc(sizeof(int) * 2 * NP1);
  double* fhS  = (double*)alloc(sizeof(double) * 2 * NP1);
  int* fhCnt   = (int*)alloc(sizeof(int) * 2);
  double* stC  = (double*)alloc(sizeof(double) * 2 * NP1);
  double* part2 = (double*)alloc(sizeof(double) * 3 * NB);
  (void)ws_size; (void)in_sizes; (void)n_in; (void)out_size;

  dim3 g2(NB, 2), blk(BS);
  dim3 gs1(NTILE, 2);

  // pass 0: keys computed on the fly from inputs
  k_hist<true><<<g2, blk, 0, stream>>>(in0, in1, nullptr, gHist, 0);
  k_scan1<<<gs1, blk, 0, stream>>>(gHist, gOfs, tileSum);
  k_scan2<<<dim3(2), dim3(NTILE), 0, stream>>>(tileSum);
  k_scatter<true><<<g2, blk, 0, stream>>>(in0, in1, nullptr, keyA, gOfs, tileSum, 0);

  u32 *kin = keyA, *kout = keyB;
  for (int p = 1; p < 4; p++) {
    k_hist<false><<<g2, blk, 0, stream>>>(nullptr, nullptr, kin, gHist, p * 8);
    k_scan1<<<gs1, blk, 0, stream>>>(gHist, gOfs, tileSum);
    k_scan2<<<dim3(2), dim3(NTILE), 0, stream>>>(tileSum);
    k_scatter<false><<<g2, blk, 0, stream>>>(nullptr, nullptr, kin, kout, gOfs, tileSum, p * 8);
    u32* tk = kin; kin = kout; kout = tk;
  }
  // sorted keys in kin (== keyB after 3 swaps)

  k_prefix1<<<g2, blk, 0, stream>>>(kin, C, bsum);
  k_prefix2<<<dim3(2), dim3(NB), 0, stream>>>(bsum);
  k_prefix3<<<g2, blk, 0, stream>>>(C, bsum, kin, candCnt);

  k_candscan<<<dim3(2), dim3(NB), 0, stream>>>(candCnt, totv);
  k_candwrite<<<g2, blk, 0, stream>>>(kin, C, candCnt, cvx, cvc);
  k_hull2<<<dim3(2), dim3(256), 0, stream>>>(cvx, cvc, totv, fhX, fhS, fhCnt, stC);

  k_rankmom<<<dim3(NB), blk, 0, stream>>>(in0, in1, kin, fhX, fhS, fhCnt, part2);
  k_final<<<dim3(1), blk, 0, stream>>>(part2, out);
}